// Round 7
// baseline (88.793 us; speedup 1.0000x reference)
//
#include <hip/hip_runtime.h>
#include <hip/hip_bf16.h>

// Sliding-window block-causal attention, grouped q-blocks, 1 barrier/iter.
// B=2 H=8 S=4096 D=64, BLK=32, W=16. f32 I/O, bf16 MFMA, in-register softmax.
// WG = 512 thr (8 waves) = QG=4 q-blocks (128 rows); wave = 16-row tile.
// Double-buffered V^T in LDS; K and V prefetched into registers one iter ahead.

#define NH    8
#define SEQ   4096
#define DIM   64
#define NBLK  128
#define WIN   16
#define QG    4
#define GROUPS (NBLK / QG)   // 32

typedef __bf16 bf16x8 __attribute__((ext_vector_type(8)));
typedef float  f32x4  __attribute__((ext_vector_type(4)));

#define VSTR 40   // Vt row stride (bf16)
#define PSTR 40   // Pb row stride (bf16)

__device__ __forceinline__ bf16x8 cvt8(f32x4 a, f32x4 b) {
    bf16x8 r;
#pragma unroll
    for (int j = 0; j < 4; ++j) { r[j] = (__bf16)a[j]; r[4 + j] = (__bf16)b[j]; }
    return r;
}

__global__ __launch_bounds__(512, 4)
void sparse_attn_v7(const float* __restrict__ Q,
                    const float* __restrict__ K,
                    const float* __restrict__ V,
                    float* __restrict__ O)
{
    // XCD-chunked bijective swizzle (512 WGs % 8 == 0)
    const int b  = (int)blockIdx.x;
    const int lg = (b & 7) * 64 + (b >> 3);
    const int bh  = lg >> 5;
    const int grp = lg & 31;
    const int n0  = grp * QG;

    const int t    = (int)threadIdx.x;
    const int wave = t >> 6;
    const int lane = t & 63;
    const int l15  = lane & 15;
    const int l4   = lane >> 4;
    const int nq   = n0 + (wave >> 1);   // this wave's q-block
    const int qtrow = wave * 16;         // row base within group (0..112)
    const int qwb  = (wave & 1) * 16 + l4 * 4; // row base within q-block (for mask)

    __shared__ unsigned short Vt[2][DIM][VSTR];   // V^T bf16, double-buffered
    __shared__ unsigned short Pb[128][PSTR];      // P bf16 (wave-local rows)

    const size_t base = (size_t)bh * SEQ * DIM;
    const float SC = 0.125f * 1.44269504088896340736f;  // d^-0.5 * log2(e)

    // ---- Q fragments (verified r4): A row = qtrow + l15, k-slot = l4*8 + j ----
    bf16x8 qf[2];
    {
        const float* qp = Q + base + (size_t)(n0 * 32 + qtrow + l15) * DIM + l4 * 8;
        qf[0] = cvt8(*(const f32x4*)qp, *(const f32x4*)(qp + 4));
        qf[1] = cvt8(*(const f32x4*)(qp + 32), *(const f32x4*)(qp + 36));
    }

    // ---- V staging coords: thread -> (key = t&31, dgroup = t>>5, 4 d's) ----
    const int vkey = t & 31;
    const int vdg  = t >> 5;   // 0..15

    const int kb0 = (n0 >= WIN - 1) ? (n0 - (WIN - 1)) : 0;
    const int kb1 = n0 + QG - 1;

    // ---- prologue: load first block's V (1 f32x4) and K (4 frags x 2 f32x4) ----
    f32x4 vcurA, vnxA;
    f32x4 kcurA[4], kcurB[4], knxA[4], knxB[4];
    {
        const float* vp = V + base + (size_t)(kb0 * 32 + vkey) * DIM + vdg * 4;
        vcurA = *(const f32x4*)vp;
#pragma unroll
        for (int f = 0; f < 4; ++f) {   // f = kh*2 + c
            const int kh = f >> 1, c = f & 1;
            const float* kp = K + base + (size_t)(kb0 * 32 + kh * 16 + l15) * DIM
                              + c * 32 + l4 * 8;
            kcurA[f] = *(const f32x4*)kp;
            kcurB[f] = *(const f32x4*)(kp + 4);
        }
    }

    f32x4 acc[4] = {};
    float m[4], l[4];
#pragma unroll
    for (int r = 0; r < 4; ++r) { m[r] = -1e30f; l[r] = 0.f; }

    for (int kb = kb0; kb <= kb1; ++kb) {
        const int  buf  = (kb - kb0) & 1;
        const bool part = (kb <= nq) && (kb >= nq - (WIN - 1));

        // ---- phase 1: write V^T tile (all threads), from prefetched regs ----
#pragma unroll
        for (int j = 0; j < 4; ++j)
            Vt[buf][vdg * 4 + j][vkey] =
                __builtin_bit_cast(unsigned short, (__bf16)vcurA[j]);

        // ---- phase 2: issue next block's global loads (latency hides below) ----
        {
            const int kbn = (kb < kb1) ? (kb + 1) : kb1;
            const float* vp = V + base + (size_t)(kbn * 32 + vkey) * DIM + vdg * 4;
            vnxA = *(const f32x4*)vp;
#pragma unroll
            for (int f = 0; f < 4; ++f) {
                const int kh = f >> 1, c = f & 1;
                const float* kp = K + base + (size_t)(kbn * 32 + kh * 16 + l15) * DIM
                                  + c * 32 + l4 * 8;
                knxA[f] = *(const f32x4*)kp;
                knxB[f] = *(const f32x4*)(kp + 4);
            }
        }

        if (part) {
            // ---- phase 3: QK^T (verified maps): 16 rows x 32 keys ----
            f32x4 s[2];
#pragma unroll
            for (int kh = 0; kh < 2; ++kh) {
                bf16x8 kf0 = cvt8(kcurA[kh * 2 + 0], kcurB[kh * 2 + 0]);
                bf16x8 kf1 = cvt8(kcurA[kh * 2 + 1], kcurB[kh * 2 + 1]);
                f32x4 a = {};
                a = __builtin_amdgcn_mfma_f32_16x16x32_bf16(qf[0], kf0, a, 0, 0, 0);
                a = __builtin_amdgcn_mfma_f32_16x16x32_bf16(qf[1], kf1, a, 0, 0, 0);
#pragma unroll
                for (int r = 0; r < 4; ++r) {
                    float sv = a[r] * SC;
                    if (kb == nq && (kh * 16 + l15) > (qwb + r)) sv = -1e30f;
                    s[kh][r] = sv;
                }
            }

            // ---- phase 4: in-register online softmax (C/D layout, r4-verified) ----
#pragma unroll
            for (int r = 0; r < 4; ++r) {
                float t0 = fmaxf(s[0][r], s[1][r]);
                t0 = fmaxf(t0, __shfl_xor(t0, 1));
                t0 = fmaxf(t0, __shfl_xor(t0, 2));
                t0 = fmaxf(t0, __shfl_xor(t0, 4));
                t0 = fmaxf(t0, __shfl_xor(t0, 8));
                const float mn = fmaxf(m[r], t0);
                const float al = exp2f(m[r] - mn);
                m[r] = mn;
                const float p0 = exp2f(s[0][r] - mn);
                const float p1 = exp2f(s[1][r] - mn);
                float ps = p0 + p1;
                ps += __shfl_xor(ps, 1);
                ps += __shfl_xor(ps, 2);
                ps += __shfl_xor(ps, 4);
                ps += __shfl_xor(ps, 8);
                l[r] = l[r] * al + ps;
#pragma unroll
                for (int dt = 0; dt < 4; ++dt) acc[dt][r] *= al;
                // P -> LDS (r5-verified roundtrip), rows wave-local
                const int prow = qtrow + l4 * 4 + r;
                Pb[prow][l15]      = __builtin_bit_cast(unsigned short, (__bf16)p0);
                Pb[prow][16 + l15] = __builtin_bit_cast(unsigned short, (__bf16)p1);
            }
        }

        __syncthreads();   // Vt[buf] staged; Pb wave-local (no barrier needed for it)

        // ---- phase 5: PV (verified r5): 4 d-tiles ----
        if (part) {
            bf16x8 pf = *reinterpret_cast<const bf16x8*>(&Pb[qtrow + l15][l4 * 8]);
#pragma unroll
            for (int dt = 0; dt < 4; ++dt) {
                bf16x8 vf = *reinterpret_cast<const bf16x8*>(
                    &Vt[buf][dt * 16 + l15][l4 * 8]);
                acc[dt] = __builtin_amdgcn_mfma_f32_16x16x32_bf16(pf, vf, acc[dt], 0, 0, 0);
            }
        }

        // ---- rotate prefetch regs ----
        vcurA = vnxA;
#pragma unroll
        for (int f = 0; f < 4; ++f) { kcurA[f] = knxA[f]; kcurB[f] = knxB[f]; }
    }

    // ---- epilogue (r6-verified): rows qtrow + l4*4 + r ----
#pragma unroll
    for (int r = 0; r < 4; ++r) {
        const int qw = qtrow + l4 * 4 + r;
        const float inv = 1.0f / l[r];
        float* op = O + base + (size_t)(n0 * 32 + qw) * DIM + l15;
        op[0]  = acc[0][r] * inv;
        op[16] = acc[1][r] * inv;
        op[32] = acc[2][r] * inv;
        op[48] = acc[3][r] * inv;
    }
}

extern "C" void kernel_launch(void* const* d_in, const int* in_sizes, int n_in,
                              void* d_out, int out_size, void* d_ws, size_t ws_size,
                              hipStream_t stream)
{
    const float* Q = (const float*)d_in[0];
    const float* K = (const float*)d_in[1];
    const float* V = (const float*)d_in[2];
    float*       O = (float*)d_out;

    const int nwg = 2 * NH * GROUPS;   // 512
    hipLaunchKernelGGL(sparse_attn_v7, dim3(nwg), dim3(512), 0, stream,
                       Q, K, V, O);
}

// Round 8
// 74.306 us; speedup vs baseline: 1.1950x; 1.1950x over previous
//
#include <hip/hip_runtime.h>
#include <hip/hip_bf16.h>

// Sliding-window block-causal attention — BARRIER-FREE independent waves.
// B=2 H=8 S=4096 D=64, BLK=32, W=16. f32 I/O, bf16 MFMA, in-reg softmax.
// WG = 256 thr (4 waves); wave = ONE q-block (32 rows), its own 16-block
// window loop. No cross-wave deps -> zero __syncthreads. Pb is wave-local
// LDS (same-wave DS ordering). K/V read direct from global (L2-resident).

#define NH    8
#define SEQ   4096
#define DIM   64
#define NBLK  128
#define WIN   16
#define QG    4
#define GROUPS (NBLK / QG)   // 32

typedef __bf16 bf16x8 __attribute__((ext_vector_type(8)));
typedef float  f32x4  __attribute__((ext_vector_type(4)));

#define PSTR 40   // Pb row stride (bf16): 80B, 16B-aligned rows

__device__ __forceinline__ bf16x8 cvt8(f32x4 a, f32x4 b) {
    bf16x8 r;
#pragma unroll
    for (int j = 0; j < 4; ++j) { r[j] = (__bf16)a[j]; r[4 + j] = (__bf16)b[j]; }
    return r;
}

__global__ __launch_bounds__(256)
void sparse_attn_v8(const float* __restrict__ Q,
                    const float* __restrict__ K,
                    const float* __restrict__ V,
                    float* __restrict__ O)
{
    // XCD-chunked bijective swizzle (512 WGs % 8 == 0)
    const int b  = (int)blockIdx.x;
    const int lg = (b & 7) * 64 + (b >> 3);
    const int bh = lg >> 5;              // 0..15
    const int n0 = (lg & 31) * QG;       // group's first q-block

    const int t    = (int)threadIdx.x;
    const int wave = t >> 6;             // 0..3
    const int lane = t & 63;
    const int l15  = lane & 15;
    const int l4   = lane >> 4;          // 0..3
    const int nq   = n0 + wave;          // this wave's q-block (one per wave)

    __shared__ unsigned short Pb[QG][32][PSTR];   // wave-local P tiles

    const size_t base = (size_t)bh * SEQ * DIM;
    const float SC = 0.125f * 1.44269504088896340736f;  // d^-0.5 * log2(e)

    // ---- Q fragments, pre-scaled by SC (verified A-map: row l15, k-slot l4*8+j)
    bf16x8 qf[2][2];   // [row-tile][k-chunk]
#pragma unroll
    for (int rt = 0; rt < 2; ++rt) {
        const float* qp = Q + base + (size_t)(nq * 32 + rt * 16 + l15) * DIM + l4 * 8;
        f32x4 a0 = *(const f32x4*)qp        * SC;
        f32x4 b0 = *(const f32x4*)(qp + 4)  * SC;
        f32x4 a1 = *(const f32x4*)(qp + 32) * SC;
        f32x4 b1 = *(const f32x4*)(qp + 36) * SC;
        qf[rt][0] = cvt8(a0, b0);
        qf[rt][1] = cvt8(a1, b1);
    }

    f32x4 acc[2][4] = {};    // [row-tile][d-tile]
    float m[2][4], l[2][4];
#pragma unroll
    for (int rt = 0; rt < 2; ++rt)
#pragma unroll
        for (int r = 0; r < 4; ++r) { m[rt][r] = -1e30f; l[rt][r] = 0.f; }

    const int kbs = (nq >= WIN - 1) ? nq - (WIN - 1) : 0;

    for (int kb = kbs; kb <= nq; ++kb) {
        // ---- K fragments direct from global (verified r6 pattern) ----
        bf16x8 kf[2][2];   // [key-half][k-chunk]
#pragma unroll
        for (int kh = 0; kh < 2; ++kh) {
            const float* kp = K + base + (size_t)(kb * 32 + kh * 16 + l15) * DIM + l4 * 8;
            kf[kh][0] = cvt8(*(const f32x4*)kp,        *(const f32x4*)(kp + 4));
            kf[kh][1] = cvt8(*(const f32x4*)(kp + 32), *(const f32x4*)(kp + 36));
        }

        // ---- V fragments direct from global (B-map: col=l15 -> d, k-slot -> key)
        // lane reads V[kb*32 + l4*8 + j][dt*16 + l15]: 16 lanes = one 64B line
        bf16x8 vf[4];
#pragma unroll
        for (int dt = 0; dt < 4; ++dt) {
            const float* vp = V + base + (size_t)(kb * 32 + l4 * 8) * DIM + dt * 16 + l15;
#pragma unroll
            for (int j = 0; j < 8; ++j) vf[dt][j] = (__bf16)vp[j * DIM];
        }

        // ---- QK^T: 32 rows x 32 keys, 8 MFMAs ----
        f32x4 s[2][2];
#pragma unroll
        for (int rt = 0; rt < 2; ++rt)
#pragma unroll
            for (int kh = 0; kh < 2; ++kh) {
                f32x4 a = {};
                a = __builtin_amdgcn_mfma_f32_16x16x32_bf16(qf[rt][0], kf[kh][0], a, 0, 0, 0);
                a = __builtin_amdgcn_mfma_f32_16x16x32_bf16(qf[rt][1], kf[kh][1], a, 0, 0, 0);
                s[rt][kh] = a;
            }

        // ---- mask (diagonal block) + in-register online softmax (verified r7)
        const bool diag = (kb == nq);
#pragma unroll
        for (int rt = 0; rt < 2; ++rt)
#pragma unroll
            for (int r = 0; r < 4; ++r) {
                float s0 = s[rt][0][r], s1 = s[rt][1][r];
                if (diag) {
                    const int qw = rt * 16 + l4 * 4 + r;   // row within q-block
                    if (l15 > qw)      s0 = -1e30f;        // keys 0..15
                    if (l15 + 16 > qw) s1 = -1e30f;        // keys 16..31
                }
                float t0 = fmaxf(s0, s1);
                t0 = fmaxf(t0, __shfl_xor(t0, 1));
                t0 = fmaxf(t0, __shfl_xor(t0, 2));
                t0 = fmaxf(t0, __shfl_xor(t0, 4));
                t0 = fmaxf(t0, __shfl_xor(t0, 8));
                const float mn = fmaxf(m[rt][r], t0);
                const float al = exp2f(m[rt][r] - mn);
                m[rt][r] = mn;
                const float p0 = exp2f(s0 - mn);
                const float p1 = exp2f(s1 - mn);
                float ps = p0 + p1;
                ps += __shfl_xor(ps, 1);
                ps += __shfl_xor(ps, 2);
                ps += __shfl_xor(ps, 4);
                ps += __shfl_xor(ps, 8);
                l[rt][r] = l[rt][r] * al + ps;
#pragma unroll
                for (int dt = 0; dt < 4; ++dt) acc[rt][dt][r] *= al;
                const int row = rt * 16 + l4 * 4 + r;
                Pb[wave][row][l15]      = __builtin_bit_cast(unsigned short, (__bf16)p0);
                Pb[wave][row][16 + l15] = __builtin_bit_cast(unsigned short, (__bf16)p1);
            }

        // ---- PV: wave-local P roundtrip (same-wave DS ordering, no barrier) ----
        bf16x8 pf0 = *(const bf16x8*)&Pb[wave][l15][l4 * 8];
        bf16x8 pf1 = *(const bf16x8*)&Pb[wave][16 + l15][l4 * 8];
#pragma unroll
        for (int dt = 0; dt < 4; ++dt) {
            acc[0][dt] = __builtin_amdgcn_mfma_f32_16x16x32_bf16(pf0, vf[dt], acc[0][dt], 0, 0, 0);
            acc[1][dt] = __builtin_amdgcn_mfma_f32_16x16x32_bf16(pf1, vf[dt], acc[1][dt], 0, 0, 0);
        }
    }

    // ---- epilogue (verified pattern) ----
#pragma unroll
    for (int rt = 0; rt < 2; ++rt)
#pragma unroll
        for (int r = 0; r < 4; ++r) {
            const int row = rt * 16 + l4 * 4 + r;
            const float inv = 1.0f / l[rt][r];
            float* op = O + base + (size_t)(nq * 32 + row) * DIM + l15;
            op[0]  = acc[rt][0][r] * inv;
            op[16] = acc[rt][1][r] * inv;
            op[32] = acc[rt][2][r] * inv;
            op[48] = acc[rt][3][r] * inv;
        }
}

extern "C" void kernel_launch(void* const* d_in, const int* in_sizes, int n_in,
                              void* d_out, int out_size, void* d_ws, size_t ws_size,
                              hipStream_t stream)
{
    const float* Q = (const float*)d_in[0];
    const float* K = (const float*)d_in[1];
    const float* V = (const float*)d_in[2];
    float*       O = (float*)d_out;

    const int nwg = 2 * NH * GROUPS;   // 512 WGs x 256 thr
    hipLaunchKernelGGL(sparse_attn_v8, dim3(nwg), dim3(256), 0, stream,
                       Q, K, V, O);
}

// Round 9
// 59.961 us; speedup vs baseline: 1.4808x; 1.2392x over previous
//
#include <hip/hip_runtime.h>
#include <hip/hip_bf16.h>

// Sliding-window block-causal attention — split-window independent waves.
// B=2 H=8 S=4096 D=64, BLK=32, W=16. f32 I/O, bf16 MFMA, in-reg softmax.
// WG = 512 thr (8 waves) = 4 q-blocks x 2 half-windows. Each wave runs the
// verified r8 loop over its 8 KV-blocks (no barriers); one end-of-kernel
// flash-merge combines the two halves. 4096 waves -> 16/CU.

#define NH    8
#define SEQ   4096
#define DIM   64
#define NBLK  128
#define WIN   16
#define QG    4
#define GROUPS (NBLK / QG)   // 32

typedef __bf16 bf16x8 __attribute__((ext_vector_type(8)));
typedef float  f32x4  __attribute__((ext_vector_type(4)));

#define PSTR 40   // Pb row stride (bf16)

__device__ __forceinline__ bf16x8 cvt8(f32x4 a, f32x4 b) {
    bf16x8 r;
#pragma unroll
    for (int j = 0; j < 4; ++j) { r[j] = (__bf16)a[j]; r[4 + j] = (__bf16)b[j]; }
    return r;
}

__global__ __launch_bounds__(512)
void sparse_attn_v9(const float* __restrict__ Q,
                    const float* __restrict__ K,
                    const float* __restrict__ V,
                    float* __restrict__ O)
{
    // XCD-chunked bijective swizzle (512 WGs % 8 == 0)
    const int b  = (int)blockIdx.x;
    const int lg = (b & 7) * 64 + (b >> 3);
    const int bh = lg >> 5;              // 0..15
    const int n0 = (lg & 31) * QG;       // group's first q-block

    const int t    = (int)threadIdx.x;
    const int wave = t >> 6;             // 0..7
    const int lane = t & 63;
    const int l15  = lane & 15;
    const int l4   = lane >> 4;          // 0..3
    const int qi   = wave >> 1;          // q-block within group: 0..3
    const int half = wave & 1;           // window half
    const int nq   = n0 + qi;            // this wave's q-block

    __shared__ unsigned short Pb[8][32][PSTR];    // wave-local P tiles (20KB)
    __shared__ float accsh[QG][32][64];           // odd-half partial acc (32KB)
    __shared__ float mlsh[QG][16][64];            // m (0..7), l (8..15) (16KB)

    const size_t base = (size_t)bh * SEQ * DIM;
    const float SC = 0.125f * 1.44269504088896340736f;  // d^-0.5 * log2(e)

    // ---- Q fragments, pre-scaled by SC (verified r8) ----
    bf16x8 qf[2][2];
#pragma unroll
    for (int rt = 0; rt < 2; ++rt) {
        const float* qp = Q + base + (size_t)(nq * 32 + rt * 16 + l15) * DIM + l4 * 8;
        f32x4 a0 = *(const f32x4*)qp        * SC;
        f32x4 b0 = *(const f32x4*)(qp + 4)  * SC;
        f32x4 a1 = *(const f32x4*)(qp + 32) * SC;
        f32x4 b1 = *(const f32x4*)(qp + 36) * SC;
        qf[rt][0] = cvt8(a0, b0);
        qf[rt][1] = cvt8(a1, b1);
    }

    f32x4 acc[2][4] = {};
    float m[2][4], l[2][4];
#pragma unroll
    for (int rt = 0; rt < 2; ++rt)
#pragma unroll
        for (int r = 0; r < 4; ++r) { m[rt][r] = -1e30f; l[rt][r] = 0.f; }

    // ---- this wave's half-window [lo, hi] ----
    const int kbs = (nq >= WIN - 1) ? nq - (WIN - 1) : 0;
    const int lo  = half ? ((nq - 7 > kbs) ? nq - 7 : kbs) : kbs;
    const int hi  = half ? nq : nq - 8;          // half0 empty if nq-8 < kbs

    for (int kb = lo; kb <= hi; ++kb) {
        // ---- K fragments direct from global (verified r8) ----
        bf16x8 kf[2][2];
#pragma unroll
        for (int kh = 0; kh < 2; ++kh) {
            const float* kp = K + base + (size_t)(kb * 32 + kh * 16 + l15) * DIM + l4 * 8;
            kf[kh][0] = cvt8(*(const f32x4*)kp,        *(const f32x4*)(kp + 4));
            kf[kh][1] = cvt8(*(const f32x4*)(kp + 32), *(const f32x4*)(kp + 36));
        }

        // ---- V fragments direct from global (verified r8) ----
        bf16x8 vf[4];
#pragma unroll
        for (int dt = 0; dt < 4; ++dt) {
            const float* vp = V + base + (size_t)(kb * 32 + l4 * 8) * DIM + dt * 16 + l15;
#pragma unroll
            for (int j = 0; j < 8; ++j) vf[dt][j] = (__bf16)vp[j * DIM];
        }

        // ---- QK^T (verified r8) ----
        f32x4 s[2][2];
#pragma unroll
        for (int rt = 0; rt < 2; ++rt)
#pragma unroll
            for (int kh = 0; kh < 2; ++kh) {
                f32x4 a = {};
                a = __builtin_amdgcn_mfma_f32_16x16x32_bf16(qf[rt][0], kf[kh][0], a, 0, 0, 0);
                a = __builtin_amdgcn_mfma_f32_16x16x32_bf16(qf[rt][1], kf[kh][1], a, 0, 0, 0);
                s[rt][kh] = a;
            }

        // ---- mask + in-register online softmax (verified r8) ----
        const bool diag = (kb == nq);
#pragma unroll
        for (int rt = 0; rt < 2; ++rt)
#pragma unroll
            for (int r = 0; r < 4; ++r) {
                float s0 = s[rt][0][r], s1 = s[rt][1][r];
                if (diag) {
                    const int qw = rt * 16 + l4 * 4 + r;
                    if (l15 > qw)      s0 = -1e30f;
                    if (l15 + 16 > qw) s1 = -1e30f;
                }
                float t0 = fmaxf(s0, s1);
                t0 = fmaxf(t0, __shfl_xor(t0, 1));
                t0 = fmaxf(t0, __shfl_xor(t0, 2));
                t0 = fmaxf(t0, __shfl_xor(t0, 4));
                t0 = fmaxf(t0, __shfl_xor(t0, 8));
                const float mn = fmaxf(m[rt][r], t0);
                const float al = exp2f(m[rt][r] - mn);
                m[rt][r] = mn;
                const float p0 = exp2f(s0 - mn);
                const float p1 = exp2f(s1 - mn);
                float ps = p0 + p1;
                ps += __shfl_xor(ps, 1);
                ps += __shfl_xor(ps, 2);
                ps += __shfl_xor(ps, 4);
                ps += __shfl_xor(ps, 8);
                l[rt][r] = l[rt][r] * al + ps;
#pragma unroll
                for (int dt = 0; dt < 4; ++dt) acc[rt][dt][r] *= al;
                const int row = rt * 16 + l4 * 4 + r;
                Pb[wave][row][l15]      = __builtin_bit_cast(unsigned short, (__bf16)p0);
                Pb[wave][row][16 + l15] = __builtin_bit_cast(unsigned short, (__bf16)p1);
            }

        // ---- PV (verified r8): wave-local P roundtrip ----
        bf16x8 pf0 = *(const bf16x8*)&Pb[wave][l15][l4 * 8];
        bf16x8 pf1 = *(const bf16x8*)&Pb[wave][16 + l15][l4 * 8];
#pragma unroll
        for (int dt = 0; dt < 4; ++dt) {
            acc[0][dt] = __builtin_amdgcn_mfma_f32_16x16x32_bf16(pf0, vf[dt], acc[0][dt], 0, 0, 0);
            acc[1][dt] = __builtin_amdgcn_mfma_f32_16x16x32_bf16(pf1, vf[dt], acc[1][dt], 0, 0, 0);
        }
    }

    // ---- flash-merge of the two halves ----
    if (half == 1) {
#pragma unroll
        for (int rt = 0; rt < 2; ++rt)
#pragma unroll
            for (int r = 0; r < 4; ++r) {
                mlsh[qi][rt * 4 + r][lane]     = m[rt][r];
                mlsh[qi][8 + rt * 4 + r][lane] = l[rt][r];
#pragma unroll
                for (int dt = 0; dt < 4; ++dt)
                    accsh[qi][(rt * 4 + dt) * 4 + r][lane] = acc[rt][dt][r];
            }
    }

    __syncthreads();

    if (half == 0) {
#pragma unroll
        for (int rt = 0; rt < 2; ++rt)
#pragma unroll
            for (int r = 0; r < 4; ++r) {
                const float m2 = mlsh[qi][rt * 4 + r][lane];
                const float l2 = mlsh[qi][8 + rt * 4 + r][lane];
                const float mn = fmaxf(m[rt][r], m2);
                const float a1 = exp2f(m[rt][r] - mn);
                const float a2 = exp2f(m2 - mn);
                const float inv = 1.0f / (l[rt][r] * a1 + l2 * a2);
                const int row = rt * 16 + l4 * 4 + r;
                float* op = O + base + (size_t)(nq * 32 + row) * DIM + l15;
#pragma unroll
                for (int dt = 0; dt < 4; ++dt) {
                    const float v = (acc[rt][dt][r] * a1 +
                                     accsh[qi][(rt * 4 + dt) * 4 + r][lane] * a2) * inv;
                    op[dt * 16] = v;
                }
            }
    }
}

extern "C" void kernel_launch(void* const* d_in, const int* in_sizes, int n_in,
                              void* d_out, int out_size, void* d_ws, size_t ws_size,
                              hipStream_t stream)
{
    const float* Q = (const float*)d_in[0];
    const float* K = (const float*)d_in[1];
    const float* V = (const float*)d_in[2];
    float*       O = (float*)d_out;

    const int nwg = 2 * NH * GROUPS;   // 512 WGs x 512 thr
    hipLaunchKernelGGL(sparse_attn_v9, dim3(nwg), dim3(512), 0, stream,
                       Q, K, V, O);
}

// Round 10
// 55.195 us; speedup vs baseline: 1.6087x; 1.0864x over previous
//
#include <hip/hip_runtime.h>
#include <hip/hip_bf16.h>

// Sliding-window block-causal attention — split-window waves + defer-max softmax.
// B=2 H=8 S=4096 D=64, BLK=32, W=16. f32 I/O, bf16 MFMA, in-reg softmax.
// WG = 512 thr (8 waves) = 4 q-blocks x 2 half-windows, barrier-free main loop.
// T13 defer-max: frozen row-max (threshold 8 in exp2 domain) -> no per-iter
// shuffle reductions, no acc rescale on the fast path. l kept as per-lane
// partials, reduced once at the end. LDS: Pb unioned with merge buffers.

#define NH    8
#define SEQ   4096
#define DIM   64
#define NBLK  128
#define WIN   16
#define QG    4
#define GROUPS (NBLK / QG)   // 32

typedef __bf16 bf16x8 __attribute__((ext_vector_type(8)));
typedef float  f32x4  __attribute__((ext_vector_type(4)));

#define PSTR 40   // Pb row stride (bf16)
#define DTHR 8.0f // defer-max threshold (exp2 domain): p <= 2^8

__device__ __forceinline__ bf16x8 cvt8(f32x4 a, f32x4 b) {
    bf16x8 r;
#pragma unroll
    for (int j = 0; j < 4; ++j) { r[j] = (__bf16)a[j]; r[4 + j] = (__bf16)b[j]; }
    return r;
}

__global__ __launch_bounds__(512)
void sparse_attn_v10(const float* __restrict__ Q,
                     const float* __restrict__ K,
                     const float* __restrict__ V,
                     float* __restrict__ O)
{
    // XCD-chunked bijective swizzle (512 WGs % 8 == 0)
    const int b  = (int)blockIdx.x;
    const int lg = (b & 7) * 64 + (b >> 3);
    const int bh = lg >> 5;
    const int n0 = (lg & 31) * QG;

    const int t    = (int)threadIdx.x;
    const int wave = t >> 6;             // 0..7
    const int lane = t & 63;
    const int l15  = lane & 15;
    const int l4   = lane >> 4;          // 0..3
    const int qi   = wave >> 1;          // q-block within group
    const int half = wave & 1;           // window half
    const int nq   = n0 + qi;

    // ---- LDS union: Pb (loop-time, 20KB) aliases merge buffers (end, 48KB) ----
    __shared__ __align__(16) char smem[49152];
    typedef unsigned short PbRow[32][PSTR];
    PbRow* Pb = (PbRow*)smem;                                  // Pb[8][32][PSTR]
    float (*accsh)[32][64] = (float (*)[32][64])smem;          // [QG][32][64]
    float (*mlsh)[16][64]  = (float (*)[16][64])(smem + 32768);// [QG][16][64]

    const size_t base = (size_t)bh * SEQ * DIM;
    const float SC = 0.125f * 1.44269504088896340736f;  // d^-0.5 * log2(e)

    // ---- Q fragments, pre-scaled by SC (verified r8) ----
    bf16x8 qf[2][2];
#pragma unroll
    for (int rt = 0; rt < 2; ++rt) {
        const float* qp = Q + base + (size_t)(nq * 32 + rt * 16 + l15) * DIM + l4 * 8;
        f32x4 a0 = *(const f32x4*)qp        * SC;
        f32x4 b0 = *(const f32x4*)(qp + 4)  * SC;
        f32x4 a1 = *(const f32x4*)(qp + 32) * SC;
        f32x4 b1 = *(const f32x4*)(qp + 36) * SC;
        qf[rt][0] = cvt8(a0, b0);
        qf[rt][1] = cvt8(a1, b1);
    }

    f32x4 acc[2][4] = {};
    float m[2][4], lp[2][4];   // lp = per-lane partial of l (2 keys/lane/iter)
#pragma unroll
    for (int rt = 0; rt < 2; ++rt)
#pragma unroll
        for (int r = 0; r < 4; ++r) { m[rt][r] = -1e30f; lp[rt][r] = 0.f; }

    const int kbs = (nq >= WIN - 1) ? nq - (WIN - 1) : 0;
    const int lo  = half ? ((nq - 7 > kbs) ? nq - 7 : kbs) : kbs;
    const int hi  = half ? nq : nq - 8;

    for (int kb = lo; kb <= hi; ++kb) {
        // ---- K fragments direct from global (verified r8) ----
        bf16x8 kf[2][2];
#pragma unroll
        for (int kh = 0; kh < 2; ++kh) {
            const float* kp = K + base + (size_t)(kb * 32 + kh * 16 + l15) * DIM + l4 * 8;
            kf[kh][0] = cvt8(*(const f32x4*)kp,        *(const f32x4*)(kp + 4));
            kf[kh][1] = cvt8(*(const f32x4*)(kp + 32), *(const f32x4*)(kp + 36));
        }

        // ---- V fragments direct from global (verified r8) ----
        bf16x8 vf[4];
#pragma unroll
        for (int dt = 0; dt < 4; ++dt) {
            const float* vp = V + base + (size_t)(kb * 32 + l4 * 8) * DIM + dt * 16 + l15;
#pragma unroll
            for (int j = 0; j < 8; ++j) vf[dt][j] = (__bf16)vp[j * DIM];
        }

        // ---- QK^T (verified r8) ----
        f32x4 s[2][2];
#pragma unroll
        for (int rt = 0; rt < 2; ++rt)
#pragma unroll
            for (int kh = 0; kh < 2; ++kh) {
                f32x4 a = {};
                a = __builtin_amdgcn_mfma_f32_16x16x32_bf16(qf[rt][0], kf[kh][0], a, 0, 0, 0);
                a = __builtin_amdgcn_mfma_f32_16x16x32_bf16(qf[rt][1], kf[kh][1], a, 0, 0, 0);
                s[rt][kh] = a;
            }

        // ---- mask (diagonal) ----
        if (kb == nq) {
#pragma unroll
            for (int rt = 0; rt < 2; ++rt)
#pragma unroll
                for (int r = 0; r < 4; ++r) {
                    const int qw = rt * 16 + l4 * 4 + r;
                    if (l15 > qw)      s[rt][0][r] = -1e30f;
                    if (l15 + 16 > qw) s[rt][1][r] = -1e30f;
                }
        }

        // ---- defer-max check (lane-local, no shuffles) ----
        bool ok = true;
#pragma unroll
        for (int rt = 0; rt < 2; ++rt)
#pragma unroll
            for (int r = 0; r < 4; ++r)
                ok &= (fmaxf(s[rt][0][r], s[rt][1][r]) <= m[rt][r] + DTHR);

        if (!__all(ok)) {
            // slow path (~first iteration only): full reduce + rescale
#pragma unroll
            for (int rt = 0; rt < 2; ++rt)
#pragma unroll
                for (int r = 0; r < 4; ++r) {
                    float t0 = fmaxf(s[rt][0][r], s[rt][1][r]);
                    t0 = fmaxf(t0, __shfl_xor(t0, 1));
                    t0 = fmaxf(t0, __shfl_xor(t0, 2));
                    t0 = fmaxf(t0, __shfl_xor(t0, 4));
                    t0 = fmaxf(t0, __shfl_xor(t0, 8));
                    const float mn = fmaxf(m[rt][r], t0);
                    const float al = exp2f(m[rt][r] - mn);
                    m[rt][r] = mn;
                    lp[rt][r] *= al;
#pragma unroll
                    for (int dt = 0; dt < 4; ++dt) acc[rt][dt][r] *= al;
                }
        }

        // ---- fast-path exp + P write + distributed l ----
#pragma unroll
        for (int rt = 0; rt < 2; ++rt)
#pragma unroll
            for (int r = 0; r < 4; ++r) {
                const float p0 = exp2f(s[rt][0][r] - m[rt][r]);
                const float p1 = exp2f(s[rt][1][r] - m[rt][r]);
                lp[rt][r] += p0 + p1;
                const int row = rt * 16 + l4 * 4 + r;
                Pb[wave][row][l15]      = __builtin_bit_cast(unsigned short, (__bf16)p0);
                Pb[wave][row][16 + l15] = __builtin_bit_cast(unsigned short, (__bf16)p1);
            }

        // ---- PV (verified r8): wave-local P roundtrip ----
        bf16x8 pf0 = *(const bf16x8*)&Pb[wave][l15][l4 * 8];
        bf16x8 pf1 = *(const bf16x8*)&Pb[wave][16 + l15][l4 * 8];
#pragma unroll
        for (int dt = 0; dt < 4; ++dt) {
            acc[0][dt] = __builtin_amdgcn_mfma_f32_16x16x32_bf16(pf0, vf[dt], acc[0][dt], 0, 0, 0);
            acc[1][dt] = __builtin_amdgcn_mfma_f32_16x16x32_bf16(pf1, vf[dt], acc[1][dt], 0, 0, 0);
        }
    }

    // ---- reduce distributed l (once) ----
    float l[2][4];
#pragma unroll
    for (int rt = 0; rt < 2; ++rt)
#pragma unroll
        for (int r = 0; r < 4; ++r) {
            float ps = lp[rt][r];
            ps += __shfl_xor(ps, 1);
            ps += __shfl_xor(ps, 2);
            ps += __shfl_xor(ps, 4);
            ps += __shfl_xor(ps, 8);
            l[rt][r] = ps;
        }

    __syncthreads();   // all waves done with Pb (aliased by merge buffers)

    // ---- flash-merge of the two halves (verified r9) ----
    if (half == 1) {
#pragma unroll
        for (int rt = 0; rt < 2; ++rt)
#pragma unroll
            for (int r = 0; r < 4; ++r) {
                mlsh[qi][rt * 4 + r][lane]     = m[rt][r];
                mlsh[qi][8 + rt * 4 + r][lane] = l[rt][r];
#pragma unroll
                for (int dt = 0; dt < 4; ++dt)
                    accsh[qi][(rt * 4 + dt) * 4 + r][lane] = acc[rt][dt][r];
            }
    }

    __syncthreads();

    if (half == 0) {
#pragma unroll
        for (int rt = 0; rt < 2; ++rt)
#pragma unroll
            for (int r = 0; r < 4; ++r) {
                const float m2 = mlsh[qi][rt * 4 + r][lane];
                const float l2 = mlsh[qi][8 + rt * 4 + r][lane];
                const float mn = fmaxf(m[rt][r], m2);
                const float a1 = exp2f(m[rt][r] - mn);
                const float a2 = exp2f(m2 - mn);
                const float inv = 1.0f / (l[rt][r] * a1 + l2 * a2);
                const int row = rt * 16 + l4 * 4 + r;
                float* op = O + base + (size_t)(nq * 32 + row) * DIM + l15;
#pragma unroll
                for (int dt = 0; dt < 4; ++dt) {
                    const float v = (acc[rt][dt][r] * a1 +
                                     accsh[qi][(rt * 4 + dt) * 4 + r][lane] * a2) * inv;
                    op[dt * 16] = v;
                }
            }
    }
}

extern "C" void kernel_launch(void* const* d_in, const int* in_sizes, int n_in,
                              void* d_out, int out_size, void* d_ws, size_t ws_size,
                              hipStream_t stream)
{
    const float* Q = (const float*)d_in[0];
    const float* K = (const float*)d_in[1];
    const float* V = (const float*)d_in[2];
    float*       O = (float*)d_out;

    const int nwg = 2 * NH * GROUPS;   // 512 WGs x 512 thr
    hipLaunchKernelGGL(sparse_attn_v10, dim3(nwg), dim3(512), 0, stream,
                       Q, K, V, O);
}

// Round 11
// 51.002 us; speedup vs baseline: 1.7410x; 1.0822x over previous
//
#include <hip/hip_runtime.h>
#include <hip/hip_bf16.h>

// Sliding-window block-causal attention — swapped-operand MFMA, LDS-free loop.
// B=2 H=8 S=4096 D=64, BLK=32, W=16. f32 I/O, bf16 MFMA, f32 softmax.
// QK^T computed as mfma(K,Q) -> S^T: lane = (query l15, key-group l4).
// Softmax axis is lane-local (defer-max fast path, no shuffles in loop).
// P packed to bf16 in regs, fed straight to PV as B-operand; V loaded with
// the SAME key permutation so the k-map cancels. Zero LDS until the merge.
// WG = 256 thr (4 waves) = 2 q-blocks x 2 half-windows; 1024 WGs.

#define NH    8
#define SEQ   4096
#define DIM   64
#define NBLK  128
#define WIN   16
#define QG    2
#define GROUPS (NBLK / QG)   // 64

typedef __bf16 bf16x8 __attribute__((ext_vector_type(8)));
typedef float  f32x4  __attribute__((ext_vector_type(4)));

#define DTHR 8.0f   // defer-max threshold (exp2 domain)

__device__ __forceinline__ bf16x8 cvt8(f32x4 a, f32x4 b) {
    bf16x8 r;
#pragma unroll
    for (int j = 0; j < 4; ++j) { r[j] = (__bf16)a[j]; r[4 + j] = (__bf16)b[j]; }
    return r;
}

__global__ __launch_bounds__(256)
void sparse_attn_v11(const float* __restrict__ Q,
                     const float* __restrict__ K,
                     const float* __restrict__ V,
                     float* __restrict__ O)
{
    // XCD-chunked bijective swizzle (1024 WGs % 8 == 0)
    const int b  = (int)blockIdx.x;
    const int lg = (b & 7) * 128 + (b >> 3);
    const int bh = lg >> 6;              // 0..15
    const int n0 = (lg & 63) * QG;       // group's first q-block

    const int t    = (int)threadIdx.x;
    const int wave = t >> 6;             // 0..3
    const int lane = t & 63;
    const int l15  = lane & 15;
    const int l4   = lane >> 4;          // 0..3
    const int qi   = wave >> 1;          // q-block within group: 0..1
    const int half = wave & 1;           // window half
    const int nq   = n0 + qi;

    __shared__ float accsh[QG][32][64];  // [qi][rt*16+dt*4+r][lane]  (16 KB)
    __shared__ float mlsh[QG][4][64];    // m: [qi][rt], l: [qi][2+rt] (2 KB)

    const size_t base = (size_t)bh * SEQ * DIM;
    const float SC = 0.125f * 1.44269504088896340736f;  // d^-0.5 * log2(e)

    // ---- Q fragments, pre-scaled (addressing identical to r4/r8-verified) ----
    bf16x8 qf[2][2];
#pragma unroll
    for (int rt = 0; rt < 2; ++rt) {
        const float* qp = Q + base + (size_t)(nq * 32 + rt * 16 + l15) * DIM + l4 * 8;
        f32x4 a0 = *(const f32x4*)qp        * SC;
        f32x4 b0 = *(const f32x4*)(qp + 4)  * SC;
        f32x4 a1 = *(const f32x4*)(qp + 32) * SC;
        f32x4 b1 = *(const f32x4*)(qp + 36) * SC;
        qf[rt][0] = cvt8(a0, b0);
        qf[rt][1] = cvt8(a1, b1);
    }

    f32x4 acc[2][4] = {};    // [rt][dt]: O[q=l15][d=dt*16+l4*4+r]
    float m[2]  = {-1e30f, -1e30f};
    float lp[2] = {0.f, 0.f};            // per-lane l partials (8 keys/iter/rt)

    const int kbs = (nq >= WIN - 1) ? nq - (WIN - 1) : 0;
    const int lo  = half ? ((nq - 7 > kbs) ? nq - 7 : kbs) : kbs;
    const int hi  = half ? nq : nq - 8;

    // V key permutation for this lane: slot j -> key kappa(l4, j)
    int vrow[8];
#pragma unroll
    for (int j = 0; j < 8; ++j)
        vrow[j] = (j < 4) ? (l4 * 4 + j) : (16 + l4 * 4 + (j - 4));

    for (int kb = lo; kb <= hi; ++kb) {
        // ---- K fragments (addressing identical to r8-verified) ----
        bf16x8 kf[2][2];
#pragma unroll
        for (int kh = 0; kh < 2; ++kh) {
            const float* kp = K + base + (size_t)(kb * 32 + kh * 16 + l15) * DIM + l4 * 8;
            kf[kh][0] = cvt8(*(const f32x4*)kp,        *(const f32x4*)(kp + 4));
            kf[kh][1] = cvt8(*(const f32x4*)(kp + 32), *(const f32x4*)(kp + 36));
        }

        // ---- V fragments, PERMUTED key map (matches P's slot map below) ----
        bf16x8 vf[4];
#pragma unroll
        for (int dt = 0; dt < 4; ++dt) {
            const float* vp = V + base + (size_t)(kb * 32) * DIM + dt * 16 + l15;
#pragma unroll
            for (int j = 0; j < 8; ++j)
                vf[dt][j] = (__bf16)vp[(size_t)vrow[j] * DIM];
        }

        // ---- swapped QK^T: s[rt][kh][r] = S[key=kh*16+l4*4+r][q=l15] ----
        f32x4 s[2][2];
#pragma unroll
        for (int rt = 0; rt < 2; ++rt)
#pragma unroll
            for (int kh = 0; kh < 2; ++kh) {
                f32x4 a = {};
                a = __builtin_amdgcn_mfma_f32_16x16x32_bf16(kf[kh][0], qf[rt][0], a, 0, 0, 0);
                a = __builtin_amdgcn_mfma_f32_16x16x32_bf16(kf[kh][1], qf[rt][1], a, 0, 0, 0);
                s[rt][kh] = a;
            }

        // ---- causal mask (diagonal block only), lane-local ----
        if (kb == nq) {
#pragma unroll
            for (int rt = 0; rt < 2; ++rt)
#pragma unroll
                for (int kh = 0; kh < 2; ++kh)
#pragma unroll
                    for (int r = 0; r < 4; ++r)
                        if (kh * 16 + l4 * 4 + r > rt * 16 + l15)
                            s[rt][kh][r] = -1e30f;
        }

        // ---- defer-max check (lane-local) ----
        bool ok = true;
#pragma unroll
        for (int rt = 0; rt < 2; ++rt)
#pragma unroll
            for (int kh = 0; kh < 2; ++kh)
#pragma unroll
                for (int r = 0; r < 4; ++r)
                    ok &= (s[rt][kh][r] <= m[rt] + DTHR);

        if (!__all(ok)) {
            // slow path (~once): reduce row-max across the 4 key-groups
#pragma unroll
            for (int rt = 0; rt < 2; ++rt) {
                float t0 = -1e30f;
#pragma unroll
                for (int kh = 0; kh < 2; ++kh)
#pragma unroll
                    for (int r = 0; r < 4; ++r) t0 = fmaxf(t0, s[rt][kh][r]);
                t0 = fmaxf(t0, __shfl_xor(t0, 16));
                t0 = fmaxf(t0, __shfl_xor(t0, 32));
                const float mn = fmaxf(m[rt], t0);
                const float al = exp2f(m[rt] - mn);
                m[rt] = mn;
                lp[rt] *= al;
#pragma unroll
                for (int dt = 0; dt < 4; ++dt)
#pragma unroll
                    for (int r = 0; r < 4; ++r) acc[rt][dt][r] *= al;
            }
        }

        // ---- exp2 + pack P to bf16 regs (slot j: kh=j>>2, r=j&3) ----
        bf16x8 pbf[2];
#pragma unroll
        for (int rt = 0; rt < 2; ++rt) {
            float psum = 0.f;
#pragma unroll
            for (int j = 0; j < 8; ++j) {
                const float p = exp2f(s[rt][j >> 2][j & 3] - m[rt]);
                psum += p;
                pbf[rt][j] = (__bf16)p;
            }
            lp[rt] += psum;
        }

        // ---- PV: mfma(A=V^T_perm, B=P_regs) -> O^T tile ----
#pragma unroll
        for (int rt = 0; rt < 2; ++rt)
#pragma unroll
            for (int dt = 0; dt < 4; ++dt)
                acc[rt][dt] = __builtin_amdgcn_mfma_f32_16x16x32_bf16(
                    vf[dt], pbf[rt], acc[rt][dt], 0, 0, 0);
    }

    // ---- final l reduction (once) ----
    float l[2];
#pragma unroll
    for (int rt = 0; rt < 2; ++rt) {
        float ps = lp[rt];
        ps += __shfl_xor(ps, 16);
        ps += __shfl_xor(ps, 32);
        l[rt] = ps;
    }

    // ---- flash-merge of the two halves ----
    if (half == 1) {
#pragma unroll
        for (int rt = 0; rt < 2; ++rt) {
            mlsh[qi][rt][lane]     = m[rt];
            mlsh[qi][2 + rt][lane] = l[rt];
#pragma unroll
            for (int dt = 0; dt < 4; ++dt)
#pragma unroll
                for (int r = 0; r < 4; ++r)
                    accsh[qi][rt * 16 + dt * 4 + r][lane] = acc[rt][dt][r];
        }
    }

    __syncthreads();

    if (half == 0) {
#pragma unroll
        for (int rt = 0; rt < 2; ++rt) {
            const float m2 = mlsh[qi][rt][lane];
            const float l2 = mlsh[qi][2 + rt][lane];
            const float mn = fmaxf(m[rt], m2);
            const float a1 = exp2f(m[rt] - mn);
            const float a2 = exp2f(m2 - mn);
            const float inv = 1.0f / (l[rt] * a1 + l2 * a2);
            // O[q = nq*32 + rt*16 + l15][d = dt*16 + l4*4 + r], f32x4 stores
            float* op = O + base + (size_t)(nq * 32 + rt * 16 + l15) * DIM + l4 * 4;
#pragma unroll
            for (int dt = 0; dt < 4; ++dt) {
                f32x4 v;
#pragma unroll
                for (int r = 0; r < 4; ++r)
                    v[r] = (acc[rt][dt][r] * a1 +
                            accsh[qi][rt * 16 + dt * 4 + r][lane] * a2) * inv;
                *(f32x4*)(op + dt * 16) = v;
            }
        }
    }
}

extern "C" void kernel_launch(void* const* d_in, const int* in_sizes, int n_in,
                              void* d_out, int out_size, void* d_ws, size_t ws_size,
                              hipStream_t stream)
{
    const float* Q = (const float*)d_in[0];
    const float* K = (const float*)d_in[1];
    const float* V = (const float*)d_in[2];
    float*       O = (float*)d_out;

    const int nwg = 2 * NH * GROUPS;   // 1024 WGs x 256 thr
    hipLaunchKernelGGL(sparse_attn_v11, dim3(nwg), dim3(256), 0, stream,
                       Q, K, V, O);
}